// Round 1
// baseline (180.748 us; speedup 1.0000x reference)
//
#include <hip/hip_runtime.h>
#include <math.h>

// Problem shape (fixed by the reference): out (32,128,128,9,5) f32, target (32,128,128,3,6) f32
constexpr int kBatch  = 32;
constexpr int kGX     = 128;
constexpr int kGY     = 128;
constexpr int kA      = 9;
constexpr int kQ      = 3;
constexpr int kNCells = kBatch * kGX * kGY;          // 524288
constexpr int kN      = kNCells * kA;                // 4718592 anchors

// acc layout (doubles): [0]=jsq (count of pos anchors), [1]=allloss, [2]=jbb, [3]=huhuh, [4]=zsd
__global__ __launch_bounds__(256)
void loss_main(const float* __restrict__ outp, const float* __restrict__ tgt,
               double* __restrict__ acc) {
    float t_jsq = 0.f, t_all = 0.f, t_jbb = 0.f, t_huh = 0.f, t_zsd = 0.f;
    const int stride = gridDim.x * blockDim.x;
    for (int idx = blockIdx.x * blockDim.x + threadIdx.x; idx < kN; idx += stride) {
        const int cell = idx / kA;                 // magic-mul div by 9
        const int gy = cell & (kGY - 1);
        const int gx = (cell >> 7) & (kGX - 1);

        const float* st = tgt + (size_t)cell * (kQ * 6);
        const float acx = st[0], acy = st[1], aw = st[2], ah = st[3], conf = st[5];
        const bool pos = conf > 0.8f;

        const float* op = outp + (size_t)idx * 5;
        const float o0 = op[0], o1 = op[1], o2 = op[2], o3 = op[3], obj = op[4];

        const float zx = (float)gx * (1.f / kGX) + 0.5f / kGX;
        const float zy = (float)gy * (1.f / kGY) + 0.5f / kGY;

        const float ax1 = acx - 0.5f * aw, ax2 = acx + 0.5f * aw;
        const float ay1 = acy - 0.5f * ah, ay2 = acy + 0.5f * ah;

        const float bcx = o0 - 0.5f + zx;
        const float bcy = o1 - 0.5f + zy;
        const float bw  = o2 - 0.5f + (1.f / kGX);
        const float bh  = o3 - 0.5f + (1.f / kGY);
        const float bx1 = bcx - 0.5f * bw, bx2 = bcx + 0.5f * bw;
        const float by1 = bcy - 0.5f * bh, by2 = bcy + 0.5f * bh;

        const float iw = fminf(ax2, bx2) - fmaxf(ax1, bx1);
        const float ih = fminf(ay2, by2) - fmaxf(ay1, by1);
        const float cross = (iw > 0.f && ih > 0.f) ? iw * ih : 0.f;
        const float uni = aw * ah + bw * bh - cross;
        const float iou = cross / (uni + 1e-6f);

        const float dx = bcx - acx, dy = bcy - acy;
        const float d2 = dx * dx + dy * dy;
        const float cw  = fmaxf(ax2, bx2) - fminf(ax1, bx1);
        const float chh = fmaxf(ay2, by2) - fminf(ay1, by1);
        const float c2 = cw * cw + chh * chh;
        const float diou = iou - d2 / c2;

        const float dat = atanf(aw / ah) - atanf(bw / bh);
        const float v = 0.4052847345693511f * dat * dat;   // 4/pi^2
        const float alpha = v / (1.f - iou + v);
        const float los = 1.f - (diou - alpha * v);
        const float om = 1.f - obj;

        // predicated accumulation (selects, no arithmetic NaN contamination)
        t_jsq += pos ? 1.f : 0.f;
        t_all += pos ? (los + om) : 0.f;
        t_jbb += pos ? iou : 0.f;
        t_huh += pos ? om : 0.f;
        t_zsd += pos ? om * om : obj * obj;
    }

    // wave-64 butterfly reduce (double), then cross-wave via LDS
    double vals[5] = {(double)t_jsq, (double)t_all, (double)t_jbb,
                      (double)t_huh, (double)t_zsd};
    #pragma unroll
    for (int i = 0; i < 5; ++i) {
        double x = vals[i];
        #pragma unroll
        for (int off = 32; off > 0; off >>= 1) x += __shfl_down(x, off, 64);
        vals[i] = x;
    }
    __shared__ double smem[4][5];
    const int lane = threadIdx.x & 63;
    const int wave = threadIdx.x >> 6;
    if (lane == 0) {
        #pragma unroll
        for (int i = 0; i < 5; ++i) smem[wave][i] = vals[i];
    }
    __syncthreads();
    if (threadIdx.x < 5) {
        const double s = smem[0][threadIdx.x] + smem[1][threadIdx.x] +
                         smem[2][threadIdx.x] + smem[3][threadIdx.x];
        atomicAdd(&acc[threadIdx.x], s);
    }
}

__global__ void loss_final(const double* __restrict__ acc, float* __restrict__ res) {
    const double jsq   = acc[0];                     // sum(pos) * A
    const double total = (double)kN;                 // jsq + qit
    res[0] = (float)(acc[1] / jsq + acc[4] / total);
    res[1] = (float)(acc[2] / jsq);
    res[2] = (float)(acc[3] / jsq);
}

extern "C" void kernel_launch(void* const* d_in, const int* in_sizes, int n_in,
                              void* d_out, int out_size, void* d_ws, size_t ws_size,
                              hipStream_t stream) {
    const float* outp = (const float*)d_in[0];   // (32,128,128,9,5)
    const float* tgt  = (const float*)d_in[1];   // (32,128,128,3,6)
    float* res = (float*)d_out;                  // 3 floats
    double* acc = (double*)d_ws;

    hipMemsetAsync(acc, 0, 5 * sizeof(double), stream);  // ws is re-poisoned each call
    loss_main<<<2048, 256, 0, stream>>>(outp, tgt, acc);
    loss_final<<<1, 1, 0, stream>>>(acc, res);
}

// Round 2
// 172.860 us; speedup vs baseline: 1.0456x; 1.0456x over previous
//
#include <hip/hip_runtime.h>
#include <math.h>

// Problem shape (fixed by the reference): out (32,128,128,9,5) f32, target (32,128,128,3,6) f32
constexpr int kBatch  = 32;
constexpr int kGX     = 128;
constexpr int kGY     = 128;
constexpr int kA      = 9;
constexpr int kNCells = kBatch * kGX * kGY;          // 524288
constexpr int kN      = kNCells * kA;                // 4718592 anchors
constexpr int kCellsPerBlock = 256;
constexpr int kBlocks = kNCells / kCellsPerBlock;    // 2048 (exact)
static_assert(kBlocks * kCellsPerBlock == kNCells, "tile must divide");

// per block: out tile = 256 cells * 45 floats = 11520 floats = 2880 float4 (46080 B)
//            tgt tile = 256 cells * 18 floats =  4608 floats = 1152 float4 (18432 B)
constexpr int kOutVec4 = kCellsPerBlock * 45 / 4;    // 2880
constexpr int kTgtVec4 = kCellsPerBlock * 18 / 4;    // 1152

__device__ inline void gload_lds16(const void* gptr, void* lptr) {
    __builtin_amdgcn_global_load_lds(
        (const __attribute__((address_space(1))) unsigned int*)gptr,
        (__attribute__((address_space(3))) unsigned int*)lptr, 16, 0, 0);
}

// acc layout (doubles): [0]=jsq count, [1]=allloss, [2]=jbb, [3]=huhuh, [4]=zsd
__global__ __launch_bounds__(256)
void loss_main(const float* __restrict__ outp, const float* __restrict__ tgt,
               double* __restrict__ acc) {
    __shared__ float4 s_out4[kOutVec4];   // 46080 B
    __shared__ float4 s_tgt4[kTgtVec4];   // 18432 B

    const int t = threadIdx.x;

    // ---- stage tiles: coalesced dwordx4 direct-to-LDS ----
    {
        const float4* g = (const float4*)outp + (size_t)blockIdx.x * kOutVec4;
        for (int i = t; i < kOutVec4; i += 256) gload_lds16(&g[i], &s_out4[i]);
        const float4* h = (const float4*)tgt + (size_t)blockIdx.x * kTgtVec4;
        for (int i = t; i < kTgtVec4; i += 256) gload_lds16(&h[i], &s_tgt4[i]);
    }
    __syncthreads();   // drains vmcnt (global_load_lds) before LDS reads

    // ---- per-thread cell compute ----
    const int cell = blockIdx.x * kCellsPerBlock + t;
    const int gy = cell & (kGY - 1);
    const int gx = (cell >> 7) & (kGX - 1);

    const float* st = (const float*)s_tgt4 + t * 18;   // row 0 of this cell's target
    const float acx = st[0], acy = st[1], aw = st[2], ah = st[3], conf = st[5];
    const bool pos = conf > 0.8f;

    // per-cell invariants (hoisted out of anchor loop)
    const float zx = (float)gx * (1.f / kGX) + 0.5f / kGX;
    const float zy = (float)gy * (1.f / kGY) + 0.5f / kGY;
    const float ax1 = acx - 0.5f * aw, ax2 = acx + 0.5f * aw;
    const float ay1 = acy - 0.5f * ah, ay2 = acy + 0.5f * ah;
    const float area_a = aw * ah;
    const float atan_a = atanf(aw / ah);

    const float* ob = (const float*)s_out4 + t * 45;

    float t_all = 0.f, t_jbb = 0.f, t_huh = 0.f, t_zsd = 0.f;
    #pragma unroll
    for (int a = 0; a < kA; ++a) {
        const float o0 = ob[a * 5 + 0], o1 = ob[a * 5 + 1], o2 = ob[a * 5 + 2];
        const float o3 = ob[a * 5 + 3], obj = ob[a * 5 + 4];

        const float bcx = o0 - 0.5f + zx;
        const float bcy = o1 - 0.5f + zy;
        const float bw  = o2 - 0.5f + (1.f / kGX);
        const float bh  = o3 - 0.5f + (1.f / kGY);
        const float bx1 = bcx - 0.5f * bw, bx2 = bcx + 0.5f * bw;
        const float by1 = bcy - 0.5f * bh, by2 = bcy + 0.5f * bh;

        const float iw = fminf(ax2, bx2) - fmaxf(ax1, bx1);
        const float ih = fminf(ay2, by2) - fmaxf(ay1, by1);
        const float cross = (iw > 0.f && ih > 0.f) ? iw * ih : 0.f;
        const float uni = area_a + bw * bh - cross;
        const float iou = cross / (uni + 1e-6f);

        const float dx = bcx - acx, dy = bcy - acy;
        const float d2 = dx * dx + dy * dy;
        const float cw  = fmaxf(ax2, bx2) - fminf(ax1, bx1);
        const float chh = fmaxf(ay2, by2) - fminf(ay1, by1);
        const float c2 = cw * cw + chh * chh;
        const float diou = iou - d2 / c2;

        const float dat = atan_a - atanf(bw / bh);
        const float v = 0.4052847345693511f * dat * dat;   // 4/pi^2
        const float alpha = v / (1.f - iou + v);
        const float los = 1.f - (diou - alpha * v);
        const float om = 1.f - obj;

        t_all += pos ? (los + om) : 0.f;
        t_jbb += pos ? iou : 0.f;
        t_huh += pos ? om : 0.f;
        t_zsd += pos ? om * om : obj * obj;
    }
    const float t_jsq = pos ? (float)kA : 0.f;

    // ---- wave-64 butterfly reduce (double), then cross-wave via LDS ----
    double vals[5] = {(double)t_jsq, (double)t_all, (double)t_jbb,
                      (double)t_huh, (double)t_zsd};
    #pragma unroll
    for (int i = 0; i < 5; ++i) {
        double x = vals[i];
        #pragma unroll
        for (int off = 32; off > 0; off >>= 1) x += __shfl_down(x, off, 64);
        vals[i] = x;
    }
    __shared__ double smem[4][5];
    const int lane = threadIdx.x & 63;
    const int wave = threadIdx.x >> 6;
    __syncthreads();   // LDS reuse: staging buffers no longer needed
    if (lane == 0) {
        #pragma unroll
        for (int i = 0; i < 5; ++i) smem[wave][i] = vals[i];
    }
    __syncthreads();
    if (threadIdx.x < 5) {
        const double s = smem[0][threadIdx.x] + smem[1][threadIdx.x] +
                         smem[2][threadIdx.x] + smem[3][threadIdx.x];
        atomicAdd(&acc[threadIdx.x], s);
    }
}

__global__ void loss_final(const double* __restrict__ acc, float* __restrict__ res) {
    const double jsq   = acc[0];                     // sum(pos) * A
    const double total = (double)kN;                 // jsq + qit
    res[0] = (float)(acc[1] / jsq + acc[4] / total);
    res[1] = (float)(acc[2] / jsq);
    res[2] = (float)(acc[3] / jsq);
}

extern "C" void kernel_launch(void* const* d_in, const int* in_sizes, int n_in,
                              void* d_out, int out_size, void* d_ws, size_t ws_size,
                              hipStream_t stream) {
    const float* outp = (const float*)d_in[0];   // (32,128,128,9,5)
    const float* tgt  = (const float*)d_in[1];   // (32,128,128,3,6)
    float* res = (float*)d_out;                  // 3 floats
    double* acc = (double*)d_ws;

    hipMemsetAsync(acc, 0, 5 * sizeof(double), stream);  // ws re-poisoned each call
    loss_main<<<kBlocks, 256, 0, stream>>>(outp, tgt, acc);
    loss_final<<<1, 1, 0, stream>>>(acc, res);
}

// Round 3
// 172.120 us; speedup vs baseline: 1.0501x; 1.0043x over previous
//
#include <hip/hip_runtime.h>
#include <math.h>

// Problem shape (fixed): out (32,128,128,9,5) f32, target (32,128,128,3,6) f32
constexpr int kGX     = 128;
constexpr int kGY     = 128;
constexpr int kA      = 9;
constexpr int kNCells = 32 * kGX * kGY;              // 524288
constexpr int kN      = kNCells * kA;                // 4718592

constexpr int kCellsPerWave = 32;
constexpr int kTiles        = kNCells / kCellsPerWave;   // 16384
constexpr int kBlocks       = 2048;
constexpr int kWavesTotal   = kBlocks * 4;               // 8192
constexpr int kTilesPerWave = kTiles / kWavesTotal;      // 2 (exact)
static_assert(kTilesPerWave * kWavesTotal == kTiles, "uniform trips");

constexpr int kOutF4 = kCellsPerWave * 45 / 4;       // 360 float4 per tile
constexpr int kTgtF4 = kCellsPerWave * 18 / 4;       // 144 float4 per tile
constexpr int kTileF4 = kOutF4 + kTgtF4;             // 504 (8064 B per wave)

__device__ inline void gload_lds16(const void* gptr, void* lptr) {
    __builtin_amdgcn_global_load_lds(
        (const __attribute__((address_space(1))) unsigned int*)gptr,
        (__attribute__((address_space(3))) unsigned int*)lptr, 16, 0, 0);
}

// acc: mode==1 -> per-block partials acc[b*5+i]; mode==0 -> 5 global doubles (atomics)
__global__ __launch_bounds__(256)
void loss_main(const float* __restrict__ outp, const float* __restrict__ tgt,
               double* __restrict__ acc, int mode) {
    __shared__ float4 s_tile[4 * kTileF4];   // 32256 B, wave-private regions
    __shared__ double smem[4][5];

    const int lane = threadIdx.x & 63;
    const int wv   = threadIdx.x >> 6;
    float4* sw = s_tile + wv * kTileF4;
    const float* swf = (const float*)sw;
    const int gwave = blockIdx.x * 4 + wv;

    float t_jsq = 0.f, t_all = 0.f, t_jbb = 0.f, t_huh = 0.f, t_zsd = 0.f;

    #pragma unroll
    for (int tt = 0; tt < kTilesPerWave; ++tt) {
        const int tile = gwave + tt * kWavesTotal;

        // ---- wave-private staging: coalesced dwordx4 direct-to-LDS ----
        const float4* g = (const float4*)outp + (size_t)tile * kOutF4;
        #pragma unroll
        for (int j = 0; j < 5; ++j) gload_lds16(&g[j * 64 + lane], &sw[j * 64 + lane]);
        if (lane < kOutF4 - 320) gload_lds16(&g[320 + lane], &sw[320 + lane]);
        const float4* h = (const float4*)tgt + (size_t)tile * kTgtF4;
        #pragma unroll
        for (int j = 0; j < 2; ++j)
            gload_lds16(&h[j * 64 + lane], &sw[kOutF4 + j * 64 + lane]);
        if (lane < kTgtF4 - 128) gload_lds16(&h[128 + lane], &sw[kOutF4 + 128 + lane]);

        // wave-level drain of this wave's LDS-DMA before ds_read (no block barrier)
        __builtin_amdgcn_s_waitcnt(0);

        // ---- compute: 2 lanes per cell; even lane anchors {0,2,4,6,8}, odd {1,3,5,7} ----
        const int c = lane >> 1;
        const int s = lane & 1;
        const int cell = tile * kCellsPerWave + c;
        const int gy = cell & (kGY - 1);
        const int gx = (cell >> 7) & (kGX - 1);

        const float* st = swf + kOutF4 * 4 + c * 18;
        const float acx = st[0], acy = st[1], aw = st[2], ah = st[3], conf = st[5];
        const bool pos = conf > 0.8f;

        const float zx = (float)gx * (1.f / kGX) + 0.5f / kGX;
        const float zy = (float)gy * (1.f / kGY) + 0.5f / kGY;
        const float ax1 = acx - 0.5f * aw, ax2 = acx + 0.5f * aw;
        const float ay1 = acy - 0.5f * ah, ay2 = acy + 0.5f * ah;
        const float area_a = aw * ah;
        const float atan_a = atanf(aw / ah);

        const float* ob = swf + c * 45 + s * 5;

        t_jsq += pos ? (s ? 4.f : 5.f) : 0.f;

        #pragma unroll
        for (int k = 0; k < 5; ++k) {
            const int a = s + 2 * k;                 // 0..8 (a==9 on odd k=4: masked)
            const bool act = (a < kA);
            const float o0 = ob[k * 10 + 0], o1 = ob[k * 10 + 1], o2 = ob[k * 10 + 2];
            const float o3 = ob[k * 10 + 3], obj = ob[k * 10 + 4];

            const float bcx = o0 - 0.5f + zx;
            const float bcy = o1 - 0.5f + zy;
            const float bw  = o2 - 0.5f + (1.f / kGX);
            const float bh  = o3 - 0.5f + (1.f / kGY);
            const float bx1 = bcx - 0.5f * bw, bx2 = bcx + 0.5f * bw;
            const float by1 = bcy - 0.5f * bh, by2 = bcy + 0.5f * bh;

            const float iw = fminf(ax2, bx2) - fmaxf(ax1, bx1);
            const float ih = fminf(ay2, by2) - fmaxf(ay1, by1);
            const float cross = (iw > 0.f && ih > 0.f) ? iw * ih : 0.f;
            const float uni = area_a + bw * bh - cross;
            const float iou = cross / (uni + 1e-6f);

            const float dx = bcx - acx, dy = bcy - acy;
            const float d2 = dx * dx + dy * dy;
            const float cw  = fmaxf(ax2, bx2) - fminf(ax1, bx1);
            const float chh = fmaxf(ay2, by2) - fminf(ay1, by1);
            const float c2 = cw * cw + chh * chh;
            const float diou = iou - d2 / c2;

            const float dat = atan_a - atanf(bw / bh);
            const float v = 0.4052847345693511f * dat * dat;   // 4/pi^2
            const float alpha = v / (1.f - iou + v);
            const float los = 1.f - (diou - alpha * v);
            const float om = 1.f - obj;

            const bool p = pos && act;
            t_all += p ? (los + om) : 0.f;
            t_jbb += p ? iou : 0.f;
            t_huh += p ? om : 0.f;
            t_zsd += p ? om * om : (act ? obj * obj : 0.f);
        }
    }

    // ---- wave-64 butterfly reduce (double), cross-wave via LDS, block partial ----
    double vals[5] = {(double)t_jsq, (double)t_all, (double)t_jbb,
                      (double)t_huh, (double)t_zsd};
    #pragma unroll
    for (int i = 0; i < 5; ++i) {
        double x = vals[i];
        #pragma unroll
        for (int off = 32; off > 0; off >>= 1) x += __shfl_down(x, off, 64);
        vals[i] = x;
    }
    if (lane == 0) {
        #pragma unroll
        for (int i = 0; i < 5; ++i) smem[wv][i] = vals[i];
    }
    __syncthreads();
    if (threadIdx.x < 5) {
        const double sv = smem[0][threadIdx.x] + smem[1][threadIdx.x] +
                          smem[2][threadIdx.x] + smem[3][threadIdx.x];
        if (mode) acc[(size_t)blockIdx.x * 5 + threadIdx.x] = sv;
        else atomicAdd(&acc[threadIdx.x], sv);
    }
}

__global__ __launch_bounds__(256)
void loss_final(const double* __restrict__ acc, float* __restrict__ res, int n_part) {
    if (n_part > 0) {
        double v[5] = {0, 0, 0, 0, 0};
        for (int j = threadIdx.x; j < n_part; j += 256) {
            #pragma unroll
            for (int i = 0; i < 5; ++i) v[i] += acc[(size_t)j * 5 + i];
        }
        #pragma unroll
        for (int i = 0; i < 5; ++i) {
            double x = v[i];
            #pragma unroll
            for (int off = 32; off > 0; off >>= 1) x += __shfl_down(x, off, 64);
            v[i] = x;
        }
        __shared__ double sm[4][5];
        const int lane = threadIdx.x & 63, wv = threadIdx.x >> 6;
        if (lane == 0) {
            #pragma unroll
            for (int i = 0; i < 5; ++i) sm[wv][i] = v[i];
        }
        __syncthreads();
        if (threadIdx.x == 0) {
            #pragma unroll
            for (int i = 0; i < 5; ++i) v[i] = sm[0][i] + sm[1][i] + sm[2][i] + sm[3][i];
            const double jsq = v[0], total = (double)kN;
            res[0] = (float)(v[1] / jsq + v[4] / total);
            res[1] = (float)(v[2] / jsq);
            res[2] = (float)(v[3] / jsq);
        }
    } else if (threadIdx.x == 0) {
        const double jsq = acc[0], total = (double)kN;
        res[0] = (float)(acc[1] / jsq + acc[4] / total);
        res[1] = (float)(acc[2] / jsq);
        res[2] = (float)(acc[3] / jsq);
    }
}

extern "C" void kernel_launch(void* const* d_in, const int* in_sizes, int n_in,
                              void* d_out, int out_size, void* d_ws, size_t ws_size,
                              hipStream_t stream) {
    const float* outp = (const float*)d_in[0];
    const float* tgt  = (const float*)d_in[1];
    float* res = (float*)d_out;
    double* acc = (double*)d_ws;

    const bool partials = ws_size >= (size_t)kBlocks * 5 * sizeof(double);  // 80 KB
    if (!partials) hipMemsetAsync(acc, 0, 5 * sizeof(double), stream);
    loss_main<<<kBlocks, 256, 0, stream>>>(outp, tgt, acc, partials ? 1 : 0);
    loss_final<<<1, 256, 0, stream>>>(acc, res, partials ? kBlocks : 0);
}

// Round 4
// 171.889 us; speedup vs baseline: 1.0515x; 1.0013x over previous
//
#include <hip/hip_runtime.h>
#include <math.h>

// Problem shape (fixed): out (32,128,128,9,5) f32, target (32,128,128,3,6) f32
constexpr int kGX     = 128;
constexpr int kGY     = 128;
constexpr int kA      = 9;
constexpr int kNCells = 32 * kGX * kGY;              // 524288
constexpr int kN      = kNCells * kA;                // 4718592

constexpr int kCellsPerWave = 32;
constexpr int kTiles        = kNCells / kCellsPerWave;   // 16384
constexpr int kBlocks       = 4096;
constexpr int kWavesTotal   = kBlocks * 4;               // 16384 == kTiles (1 tile/wave)
static_assert(kWavesTotal == kTiles, "one tile per wave");

constexpr int kOutF4 = kCellsPerWave * 45 / 4;       // 360 float4 per tile
constexpr int kTgtF4 = kCellsPerWave * 18 / 4;       // 144 float4 per tile
constexpr int kTileF4 = kOutF4 + kTgtF4;             // 504 (8064 B per wave)

__device__ inline void gload_lds16(const void* gptr, void* lptr) {
    __builtin_amdgcn_global_load_lds(
        (const __attribute__((address_space(1))) unsigned int*)gptr,
        (__attribute__((address_space(3))) unsigned int*)lptr, 16, 0, 0);
}

__device__ inline float frcp(float x) { return __builtin_amdgcn_rcpf(x); }

// Branchless full-range atan, A&S 4.4.49 poly on [0,1] (|eps| <= 1e-5).
__device__ inline float fast_atan(float r) {
    const float x = fabsf(r);
    const bool inv = x > 1.f;
    const float t = inv ? frcp(x) : x;
    const float t2 = t * t;
    float p = fmaf(t2, 0.0208351f, -0.0851330f);
    p = fmaf(t2, p, 0.1801410f);
    p = fmaf(t2, p, -0.3302995f);
    p = fmaf(t2, p, 0.9998660f);
    p = t * p;
    float res = inv ? (1.5707963f - p) : p;
    return r < 0.f ? -res : res;
}

// acc: mode==1 -> per-block partials acc[b*5+i]; mode==0 -> 5 global doubles (atomics)
__global__ __launch_bounds__(256)
void loss_main(const float* __restrict__ outp, const float* __restrict__ tgt,
               double* __restrict__ acc, int mode) {
    __shared__ float4 s_tile[4 * kTileF4];   // 32256 B, wave-private regions
    __shared__ double smem[4][5];

    const int lane = threadIdx.x & 63;
    const int wv   = threadIdx.x >> 6;
    float4* sw = s_tile + wv * kTileF4;
    const float* swf = (const float*)sw;
    const int tile = blockIdx.x * 4 + wv;    // 1 tile per wave

    // ---- wave-private staging: coalesced dwordx4 direct-to-LDS ----
    {
        const float4* g = (const float4*)outp + (size_t)tile * kOutF4;
        #pragma unroll
        for (int j = 0; j < 5; ++j) gload_lds16(&g[j * 64 + lane], &sw[j * 64 + lane]);
        if (lane < kOutF4 - 320) gload_lds16(&g[320 + lane], &sw[320 + lane]);
        const float4* h = (const float4*)tgt + (size_t)tile * kTgtF4;
        #pragma unroll
        for (int j = 0; j < 2; ++j)
            gload_lds16(&h[j * 64 + lane], &sw[kOutF4 + j * 64 + lane]);
        if (lane < kTgtF4 - 128) gload_lds16(&h[128 + lane], &sw[kOutF4 + 128 + lane]);
    }
    // wave-level drain of this wave's LDS-DMA before ds_read (no block barrier)
    __builtin_amdgcn_s_waitcnt(0);

    // ---- compute: 2 lanes per cell; even lane anchors {0,2,4,6,8}, odd {1,3,5,7} ----
    const int c = lane >> 1;
    const int s = lane & 1;
    const int cell = tile * kCellsPerWave + c;
    const int gy = cell & (kGY - 1);
    const int gx = (cell >> 7) & (kGX - 1);

    const float* st = swf + kOutF4 * 4 + c * 18;
    const float acx = st[0], acy = st[1], aw = st[2], ah = st[3], conf = st[5];
    const bool pos = conf > 0.8f;

    const float zx = (float)gx * (1.f / kGX) + 0.5f / kGX;
    const float zy = (float)gy * (1.f / kGY) + 0.5f / kGY;
    const float ax1 = acx - 0.5f * aw, ax2 = acx + 0.5f * aw;
    const float ay1 = acy - 0.5f * ah, ay2 = acy + 0.5f * ah;
    const float area_a = aw * ah;
    const float atan_a = fast_atan(aw * frcp(ah));

    const float* ob = swf + c * 45 + s * 5;

    float t_all = 0.f, t_jbb = 0.f, t_huh = 0.f, t_zsd = 0.f;
    float t_jsq = pos ? (s ? 4.f : 5.f) : 0.f;

    #pragma unroll
    for (int k = 0; k < 5; ++k) {
        const int a = s + 2 * k;                 // 0..8 (a==9 on odd k=4: masked)
        const bool act = (a < kA);
        const float o0 = ob[k * 10 + 0], o1 = ob[k * 10 + 1], o2 = ob[k * 10 + 2];
        const float o3 = ob[k * 10 + 3], obj = ob[k * 10 + 4];

        const float bcx = o0 - 0.5f + zx;
        const float bcy = o1 - 0.5f + zy;
        const float bw  = o2 - 0.5f + (1.f / kGX);
        const float bh  = o3 - 0.5f + (1.f / kGY);
        const float bx1 = bcx - 0.5f * bw, bx2 = bcx + 0.5f * bw;
        const float by1 = bcy - 0.5f * bh, by2 = bcy + 0.5f * bh;

        const float iw = fminf(ax2, bx2) - fmaxf(ax1, bx1);
        const float ih = fminf(ay2, by2) - fmaxf(ay1, by1);
        const float cross = (iw > 0.f && ih > 0.f) ? iw * ih : 0.f;
        const float uni = area_a + bw * bh - cross;
        const float iou = cross * frcp(uni + 1e-6f);

        const float dx = bcx - acx, dy = bcy - acy;
        const float d2 = dx * dx + dy * dy;
        const float cw  = fmaxf(ax2, bx2) - fminf(ax1, bx1);
        const float chh = fmaxf(ay2, by2) - fminf(ay1, by1);
        const float c2 = cw * cw + chh * chh;
        const float diou = iou - d2 * frcp(c2);

        const float dat = atan_a - fast_atan(bw * frcp(bh));
        const float v = 0.4052847345693511f * dat * dat;   // 4/pi^2
        const float alpha = v * frcp(1.f - iou + v);
        const float los = 1.f - (diou - alpha * v);
        const float om = 1.f - obj;

        const bool p = pos && act;
        t_all += p ? (los + om) : 0.f;
        t_jbb += p ? iou : 0.f;
        t_huh += p ? om : 0.f;
        t_zsd += p ? om * om : (act ? obj * obj : 0.f);
    }

    // ---- wave-64 butterfly reduce (double), cross-wave via LDS, block partial ----
    double vals[5] = {(double)t_jsq, (double)t_all, (double)t_jbb,
                      (double)t_huh, (double)t_zsd};
    #pragma unroll
    for (int i = 0; i < 5; ++i) {
        double x = vals[i];
        #pragma unroll
        for (int off = 32; off > 0; off >>= 1) x += __shfl_down(x, off, 64);
        vals[i] = x;
    }
    if (lane == 0) {
        #pragma unroll
        for (int i = 0; i < 5; ++i) smem[wv][i] = vals[i];
    }
    __syncthreads();
    if (threadIdx.x < 5) {
        const double sv = smem[0][threadIdx.x] + smem[1][threadIdx.x] +
                          smem[2][threadIdx.x] + smem[3][threadIdx.x];
        if (mode) acc[(size_t)blockIdx.x * 5 + threadIdx.x] = sv;
        else atomicAdd(&acc[threadIdx.x], sv);
    }
}

__global__ __launch_bounds__(256)
void loss_final(const double* __restrict__ acc, float* __restrict__ res, int n_part) {
    if (n_part > 0) {
        double v[5] = {0, 0, 0, 0, 0};
        for (int j = threadIdx.x; j < n_part; j += 256) {
            #pragma unroll
            for (int i = 0; i < 5; ++i) v[i] += acc[(size_t)j * 5 + i];
        }
        #pragma unroll
        for (int i = 0; i < 5; ++i) {
            double x = v[i];
            #pragma unroll
            for (int off = 32; off > 0; off >>= 1) x += __shfl_down(x, off, 64);
            v[i] = x;
        }
        __shared__ double sm[4][5];
        const int lane = threadIdx.x & 63, wv = threadIdx.x >> 6;
        if (lane == 0) {
            #pragma unroll
            for (int i = 0; i < 5; ++i) sm[wv][i] = v[i];
        }
        __syncthreads();
        if (threadIdx.x == 0) {
            #pragma unroll
            for (int i = 0; i < 5; ++i) v[i] = sm[0][i] + sm[1][i] + sm[2][i] + sm[3][i];
            const double jsq = v[0], total = (double)kN;
            res[0] = (float)(v[1] / jsq + v[4] / total);
            res[1] = (float)(v[2] / jsq);
            res[2] = (float)(v[3] / jsq);
        }
    } else if (threadIdx.x == 0) {
        const double jsq = acc[0], total = (double)kN;
        res[0] = (float)(acc[1] / jsq + acc[4] / total);
        res[1] = (float)(acc[2] / jsq);
        res[2] = (float)(acc[3] / jsq);
    }
}

extern "C" void kernel_launch(void* const* d_in, const int* in_sizes, int n_in,
                              void* d_out, int out_size, void* d_ws, size_t ws_size,
                              hipStream_t stream) {
    const float* outp = (const float*)d_in[0];
    const float* tgt  = (const float*)d_in[1];
    float* res = (float*)d_out;
    double* acc = (double*)d_ws;

    const bool partials = ws_size >= (size_t)kBlocks * 5 * sizeof(double);  // 160 KB
    if (!partials) hipMemsetAsync(acc, 0, 5 * sizeof(double), stream);
    loss_main<<<kBlocks, 256, 0, stream>>>(outp, tgt, acc, partials ? 1 : 0);
    loss_final<<<1, 256, 0, stream>>>(acc, res, partials ? kBlocks : 0);
}